// Round 20
// baseline (49.081 us; speedup 1.0000x reference)
//
#include <hip/hip_runtime.h>

#define NH   8
#define SEQ  2048
#define DIM  512
#define EMB  512
#define DH   64
#define HALF 128
#define QT   32           // queries per attn block (2 halves of 16)
#define KW2  288          // QT + 2*HALF
#define SCS2 292          // Sc row stride (f32)

typedef __attribute__((ext_vector_type(8))) short short8;
typedef __attribute__((ext_vector_type(4))) float f32x4;

__device__ __forceinline__ unsigned short f2bf(float f) {
    unsigned int u = __float_as_uint(f);
    return (unsigned short)((u + 0x7fffu + ((u >> 16) & 1u)) >> 16);
}

__device__ __forceinline__ void gload_lds16(const void* g, void* l) {
    __builtin_amdgcn_global_load_lds((__attribute__((address_space(1))) void*)g,
                                     (__attribute__((address_space(3))) void*)l,
                                     16, 0, 0);
}

// one kernel converts x, Wqkv, Wo -> contiguous bf16 region (3072 blocks)
__global__ __launch_bounds__(256)
void cvt_all(const float* __restrict__ x, const float* __restrict__ wqkv,
             const float* __restrict__ wo, unsigned short* __restrict__ out) {
    const int i = blockIdx.x * 256 + threadIdx.x;   // float4 index, grid exact
    const float* src;
    int base;
    if (i < 524288)      { src = x;    base = 0; }
    else if (i < 720896) { src = wqkv; base = 524288; }
    else                 { src = wo;   base = 720896; }
    float4 v = ((const float4*)src)[i - base];
    ((ushort4*)out)[i] = make_ushort4(f2bf(v.x), f2bf(v.y), f2bf(v.z), f2bf(v.w));
}

// qkv projection from bf16 inputs, pure global_load_lds staging.
// 64x64 tiles, BK=128, 1536 blocks (~5 blocks/CU: occupancy over reuse),
// XCD-swizzled. Each tile lies in exactly one (h, q/k/v) plane.
// Q,K -> qkvh[b][h][ty][s][d] packed; V -> vT[b][h][d][s] packed.
__global__ __launch_bounds__(256)
void gemm_qkv(const unsigned short* __restrict__ A, const unsigned short* __restrict__ B,
              const float* __restrict__ bias, unsigned short* __restrict__ qkvh,
              unsigned short* __restrict__ vT) {
    constexpr int BM = 64, BN = 64, BK = 128;
    __shared__ unsigned short As[BM * BK];   // [64][128] swizzled, 16 KB
    __shared__ unsigned short Bs[BN * BK];   // [64][128] swizzled, 16 KB
    const int bid = blockIdx.x;
    const int wg = (bid & 7) * 192 + (bid >> 3);    // XCD-local A panels (1536=8*192)
    const int bm = (wg / 24) * BM, bn = (wg % 24) * BN;
    const int t = threadIdx.x, lane = t & 63, wid = t >> 6;
    const int wr = wid >> 1, wc = wid & 1;
    const int lr = lane & 15, lg = lane >> 4;

    f32x4 acc[2][2];
    #pragma unroll
    for (int m = 0; m < 2; ++m)
        #pragma unroll
        for (int n = 0; n < 2; ++n)
            acc[m][n] = (f32x4){0.f, 0.f, 0.f, 0.f};

    for (int kt = 0; kt < DIM; kt += BK) {
        #pragma unroll
        for (int off = 0; off < BM * BK; off += 2048) {
            const int e = off + t * 8, r = e >> 7, c4 = (e & 127) >> 3;
            const int gc = (c4 ^ (r & 7)) << 3;
            gload_lds16(A + (size_t)(bm + r) * DIM + kt + gc, &As[e]);
        }
        #pragma unroll
        for (int off = 0; off < BN * BK; off += 2048) {
            const int e = off + t * 8, r = e >> 7, c4 = (e & 127) >> 3;
            const int gc = (c4 ^ (r & 7)) << 3;
            gload_lds16(B + (size_t)(bn + r) * DIM + kt + gc, &Bs[e]);
        }
        __syncthreads();
        #pragma unroll
        for (int kk = 0; kk < 4; ++kk) {
            short8 af[2], bf[2];
            #pragma unroll
            for (int m = 0; m < 2; ++m) {
                const int row = wr * 32 + m * 16 + lr;
                af[m] = *(const short8*)&As[row * BK + (((kk * 4 + lg) ^ (row & 7)) << 3)];
            }
            #pragma unroll
            for (int n = 0; n < 2; ++n) {
                const int row = wc * 32 + n * 16 + lr;
                bf[n] = *(const short8*)&Bs[row * BK + (((kk * 4 + lg) ^ (row & 7)) << 3)];
            }
            #pragma unroll
            for (int m = 0; m < 2; ++m)
                #pragma unroll
                for (int n = 0; n < 2; ++n)
                    acc[m][n] = __builtin_amdgcn_mfma_f32_16x16x32_bf16(af[m], bf[n], acc[m][n], 0, 0, 0);
        }
        __syncthreads();
    }

    // epilogue: acc -> Tr[64][72] bf16 (reuse As), then packed stores
    unsigned short* Tr = As;
    #pragma unroll
    for (int n = 0; n < 2; ++n) {
        const int cl = wc * 32 + n * 16 + lr;
        const float bv = bias[bn + cl];
        #pragma unroll
        for (int m = 0; m < 2; ++m)
            #pragma unroll
            for (int r = 0; r < 4; ++r)
                Tr[(wr * 32 + m * 16 + lg * 4 + r) * 72 + cl] = f2bf(acc[m][n][r] + bv);
    }
    __syncthreads();

    const int h = bn / 192, ty = (bn >> 6) % 3;
    const int bb = bm >> 11, s0 = bm & 2047;
    if (ty < 2) {   // Q,K: contiguous [s][d] rows; thread -> (s = t>>2, 16 cols)
        unsigned short* plane = qkvh + (((size_t)(bb * NH + h) * 3 + ty) * SEQ) * DH;
        const int s = t >> 2, hf = (t & 3) * 16;
        unsigned short* dst = plane + (size_t)(s0 + s) * DH + hf;
        *(short8*)&dst[0] = *(const short8*)&Tr[s * 72 + hf];
        *(short8*)&dst[8] = *(const short8*)&Tr[s * 72 + hf + 8];
    } else {        // V: transposed packed [d][s] stores; thread -> (d = t>>2, 16 s)
        const int d = t >> 2, pp = t & 3;
        unsigned short* vrow = vT + ((size_t)(bb * NH + h) * DH + d) * SEQ + s0 + pp * 16;
        alignas(16) unsigned short tmp[16];
        #pragma unroll
        for (int k = 0; k < 16; ++k) tmp[k] = Tr[(pp * 16 + k) * 72 + d];
        *(short8*)&vrow[0] = *(short8*)&tmp[0];
        *(short8*)&vrow[8] = *(short8*)&tmp[8];
    }
}

// MFMA windowed attention, QT=32, destaged (R19 exact).
__global__ __launch_bounds__(256)
void attn_mfma(const unsigned short* __restrict__ qkvh,
               const unsigned short* __restrict__ vT,
               const int* __restrict__ pad,
               unsigned short* __restrict__ Yb) {
    const int bid = blockIdx.x;
    const int wg = (bid & 7) * 128 + (bid >> 3);     // XCD-local K/V planes
    const int bh = wg >> 6, qt = wg & 63;
    const int b = bh >> 3, h = bh & 7;
    const int i0 = qt * QT, kb = i0 - HALF;
    const int t = threadIdx.x, lane = t & 63, w = t >> 6;
    const int lr = lane & 15, lg = lane >> 4;

    __shared__ float Sc[QT * SCS2];                  // 37376 B

    const unsigned short* Qg = qkvh + ((size_t)bh * 3 + 0) * SEQ * DH;
    const unsigned short* Kg = qkvh + ((size_t)bh * 3 + 1) * SEQ * DH;
    const unsigned short* vTg = vT + (size_t)bh * DH * SEQ;
    const int* padb = pad + b * SEQ;

    short8 qf[2][2];
    #pragma unroll
    for (int half = 0; half < 2; ++half)
        #pragma unroll
        for (int kk = 0; kk < 2; ++kk)
            qf[half][kk] = *(const short8*)&Qg[(size_t)(i0 + half * 16 + lr) * DH + kk * 32 + lg * 8];

    #pragma unroll
    for (int it = 0; it < 5; ++it) {
        const int tile = w + it * 4;
        if (tile < 18) {
            const int jl = tile * 16 + lr;
            const int j = kb + jl;
            const int jc = j < 0 ? 0 : (j > SEQ - 1 ? SEQ - 1 : j);
            const int kv = (j >= 0 && j < SEQ) ? padb[j] : 0;
            f32x4 a0 = (f32x4){0.f, 0.f, 0.f, 0.f};
            f32x4 a1 = (f32x4){0.f, 0.f, 0.f, 0.f};
            __builtin_amdgcn_s_setprio(1);
            #pragma unroll
            for (int kk = 0; kk < 2; ++kk) {
                const short8 bfr = *(const short8*)&Kg[(size_t)jc * DH + kk * 32 + lg * 8];
                a0 = __builtin_amdgcn_mfma_f32_16x16x32_bf16(qf[0][kk], bfr, a0, 0, 0, 0);
                a1 = __builtin_amdgcn_mfma_f32_16x16x32_bf16(qf[1][kk], bfr, a1, 0, 0, 0);
            }
            __builtin_amdgcn_s_setprio(0);
            #pragma unroll
            for (int r = 0; r < 4; ++r) {
                const int q0 = lg * 4 + r, q1 = 16 + q0;
                const bool ok0 = kv && (jl >= q0) && (jl <= q0 + 2 * HALF);
                const bool ok1 = kv && (jl >= q1) && (jl <= q1 + 2 * HALF);
                Sc[q0 * SCS2 + jl] = ok0 ? a0[r] * 0.125f : -1e30f;
                Sc[q1 * SCS2 + jl] = ok1 ? a1[r] * 0.125f : -1e30f;
            }
        }
    }
    __syncthreads();

    #pragma unroll
    for (int u8 = 0; u8 < 8; ++u8) {
        const int r = w + u8 * 4;
        float* row = &Sc[r * SCS2];
        unsigned short* prow = (unsigned short*)row;
        if (!padb[i0 + r]) {
            #pragma unroll
            for (int u = 0; u < 5; ++u) {
                const int jl = lane + 64 * u;
                if (jl < KW2) prow[jl] = 0;
            }
            continue;
        }
        float v[5];
        float mx = -1e30f;
        #pragma unroll
        for (int u = 0; u < 5; ++u) {
            const int jl = lane + 64 * u;
            v[u] = (jl < KW2) ? row[jl] : -1e30f;
            mx = fmaxf(mx, v[u]);
        }
        #pragma unroll
        for (int off = 32; off; off >>= 1) mx = fmaxf(mx, __shfl_xor(mx, off));
        float s = 0.f;
        #pragma unroll
        for (int u = 0; u < 5; ++u) { v[u] = __expf(v[u] - mx); s += v[u]; }
        #pragma unroll
        for (int off = 32; off; off >>= 1) s += __shfl_xor(s, off);
        const float inv = 1.f / s;
        asm volatile("" ::: "memory");
        #pragma unroll
        for (int u = 0; u < 5; ++u) {
            const int jl = lane + 64 * u;
            if (jl < KW2) prow[jl] = f2bf(v[u] * inv);
        }
    }
    __syncthreads();

    f32x4 o0 = (f32x4){0.f, 0.f, 0.f, 0.f};
    f32x4 o1 = (f32x4){0.f, 0.f, 0.f, 0.f};
    const unsigned short* PbU = (const unsigned short*)Sc;
    const int d0 = w * 16 + lr;
    #pragma unroll
    for (int c = 0; c < 9; ++c) {
        int j0 = kb + c * 32 + lg * 8;
        j0 = j0 < 0 ? 0 : (j0 > SEQ - 8 ? SEQ - 8 : j0);
        const short8 vf  = *(const short8*)&vTg[(size_t)d0 * SEQ + j0];
        const short8 pf0 = *(const short8*)&PbU[lr * (SCS2 * 2) + c * 32 + lg * 8];
        const short8 pf1 = *(const short8*)&PbU[(16 + lr) * (SCS2 * 2) + c * 32 + lg * 8];
        __builtin_amdgcn_s_setprio(1);
        o0 = __builtin_amdgcn_mfma_f32_16x16x32_bf16(pf0, vf, o0, 0, 0, 0);
        o1 = __builtin_amdgcn_mfma_f32_16x16x32_bf16(pf1, vf, o1, 0, 0, 0);
        __builtin_amdgcn_s_setprio(0);
    }

    #pragma unroll
    for (int r = 0; r < 4; ++r) {
        Yb[(size_t)(b * SEQ + i0 + lg * 4 + r) * EMB + h * DH + d0]      = f2bf(o0[r]);
        Yb[(size_t)(b * SEQ + i0 + 16 + lg * 4 + r) * EMB + h * DH + d0] = f2bf(o1[r]);
    }
}

// out = Yb(bf16) @ Wo(bf16)^T + bo. 64x64 tiles, BK=128, 512 blocks (R19 exact).
__global__ __launch_bounds__(256)
void gemm_out(const unsigned short* __restrict__ A, const unsigned short* __restrict__ B,
              const float* __restrict__ bias, float* __restrict__ C) {
    constexpr int BM = 64, BN = 64, BK = 128;
    __shared__ unsigned short As[BM * BK];   // 16 KB
    __shared__ unsigned short Bs[BN * BK];   // 16 KB
    const int bid = blockIdx.x;
    const int wg = (bid & 7) * 64 + (bid >> 3);      // XCD-local A panels
    const int bm = (wg >> 3) * BM, bn = (wg & 7) * BN;
    const int t = threadIdx.x, lane = t & 63, wid = t >> 6;
    const int wr = wid >> 1, wc = wid & 1;
    const int lr = lane & 15, lg = lane >> 4;

    f32x4 acc[2][2];
    #pragma unroll
    for (int m = 0; m < 2; ++m)
        #pragma unroll
        for (int n = 0; n < 2; ++n)
            acc[m][n] = (f32x4){0.f, 0.f, 0.f, 0.f};

    for (int kt = 0; kt < DIM; kt += BK) {
        #pragma unroll
        for (int off = 0; off < BM * BK; off += 2048) {
            const int e = off + t * 8, r = e >> 7, c4 = (e & 127) >> 3;
            const int gc = (c4 ^ (r & 7)) << 3;
            gload_lds16(A + (size_t)(bm + r) * EMB + kt + gc, &As[e]);
        }
        #pragma unroll
        for (int off = 0; off < BN * BK; off += 2048) {
            const int e = off + t * 8, r = e >> 7, c4 = (e & 127) >> 3;
            const int gc = (c4 ^ (r & 7)) << 3;
            gload_lds16(B + (size_t)(bn + r) * DIM + kt + gc, &Bs[e]);
        }
        __syncthreads();
        #pragma unroll
        for (int kk = 0; kk < 4; ++kk) {
            short8 af[2], bf[2];
            #pragma unroll
            for (int m = 0; m < 2; ++m) {
                const int row = wr * 32 + m * 16 + lr;
                af[m] = *(const short8*)&As[row * BK + (((kk * 4 + lg) ^ (row & 7)) << 3)];
            }
            #pragma unroll
            for (int n = 0; n < 2; ++n) {
                const int row = wc * 32 + n * 16 + lr;
                bf[n] = *(const short8*)&Bs[row * BK + (((kk * 4 + lg) ^ (row & 7)) << 3)];
            }
            #pragma unroll
            for (int m = 0; m < 2; ++m)
                #pragma unroll
                for (int n = 0; n < 2; ++n)
                    acc[m][n] = __builtin_amdgcn_mfma_f32_16x16x32_bf16(af[m], bf[n], acc[m][n], 0, 0, 0);
        }
        __syncthreads();
    }

    const int orow = bm + wr * 32 + lg * 4;
    const int oc0 = bn + wc * 32 + lr;
    #pragma unroll
    for (int m = 0; m < 2; ++m)
        #pragma unroll
        for (int n = 0; n < 2; ++n) {
            const int col = oc0 + n * 16;
            const float bv = bias[col];
            #pragma unroll
            for (int r = 0; r < 4; ++r)
                C[(size_t)(orow + m * 16 + r) * EMB + col] = acc[m][n][r] + bv;
        }
}

extern "C" void kernel_launch(void* const* d_in, const int* in_sizes, int n_in,
                              void* d_out, int out_size, void* d_ws, size_t ws_size,
                              hipStream_t stream) {
    const float* x    = (const float*)d_in[0];
    const int*   pad  = (const int*)d_in[1];
    const float* Wqkv = (const float*)d_in[2];
    const float* bqkv = (const float*)d_in[3];
    const float* Wo   = (const float*)d_in[4];
    const float* bo   = (const float*)d_in[5];
    float* out = (float*)d_out;

    char* p = (char*)d_ws;
    unsigned short* qkvh  = (unsigned short*)p;                   // 12.6 MB (Q,K planes)
    unsigned short* vT    = (unsigned short*)(p + 12582912);      // 4 MB
    unsigned short* Yb    = (unsigned short*)(p + 16777216);      // 4 MB
    unsigned short* cvtb  = (unsigned short*)(p + 20971520);      // 6 MB: xb|wqkvb|wob
    unsigned short* xb    = cvtb;
    unsigned short* wqkvb = cvtb + 2097152;
    unsigned short* wob   = cvtb + 2883584;

    dim3 blk(256);
    cvt_all<<<dim3(3072), blk, 0, stream>>>(x, Wqkv, Wo, cvtb);
    gemm_qkv<<<dim3(1536), blk, 0, stream>>>(xb, wqkvb, bqkv, qkvh, vT);
    attn_mfma<<<dim3(1024), blk, 0, stream>>>(qkvh, vT, pad, Yb);
    gemm_out<<<dim3(512), blk, 0, stream>>>(Yb, wob, bo, out);
}

// Round 21
// 48.491 us; speedup vs baseline: 1.0122x; 1.0122x over previous
//
#include <hip/hip_runtime.h>

#define NH   8
#define SEQ  2048
#define DIM  512
#define EMB  512
#define DH   64
#define HALF 128
#define QT   32           // queries per attn block (2 halves of 16)
#define KW2  288          // QT + 2*HALF
#define SCS2 292          // Sc row stride (f32)

typedef __attribute__((ext_vector_type(8))) short short8;
typedef __attribute__((ext_vector_type(4))) float f32x4;

__device__ __forceinline__ unsigned short f2bf(float f) {
    unsigned int u = __float_as_uint(f);
    return (unsigned short)((u + 0x7fffu + ((u >> 16) & 1u)) >> 16);
}

__device__ __forceinline__ void gload_lds16(const void* g, void* l) {
    __builtin_amdgcn_global_load_lds((__attribute__((address_space(1))) void*)g,
                                     (__attribute__((address_space(3))) void*)l,
                                     16, 0, 0);
}

// one kernel converts x, Wqkv, Wo -> contiguous bf16 region (3072 blocks)
__global__ __launch_bounds__(256)
void cvt_all(const float* __restrict__ x, const float* __restrict__ wqkv,
             const float* __restrict__ wo, unsigned short* __restrict__ out) {
    const int i = blockIdx.x * 256 + threadIdx.x;   // float4 index, grid exact
    const float* src;
    int base;
    if (i < 524288)      { src = x;    base = 0; }
    else if (i < 720896) { src = wqkv; base = 524288; }
    else                 { src = wo;   base = 720896; }
    float4 v = ((const float4*)src)[i - base];
    ((ushort4*)out)[i] = make_ushort4(f2bf(v.x), f2bf(v.y), f2bf(v.z), f2bf(v.w));
}

// qkv projection from bf16 inputs, pure global_load_lds staging.
// 128x64 tiles, BK=128 (4 K-iters), 768 blocks, XCD-swizzled.
// Q,K -> qkvh[b][h][ty][s][d]; V -> vT[b][h][d][s].
__global__ __launch_bounds__(256)
void gemm_qkv(const unsigned short* __restrict__ A, const unsigned short* __restrict__ B,
              const float* __restrict__ bias, unsigned short* __restrict__ qkvh,
              unsigned short* __restrict__ vT) {
    constexpr int BM = 128, BN = 64, BK = 128;
    __shared__ unsigned short As[BM * BK];   // [128][128] swizzled, 32 KB
    __shared__ unsigned short Bs[BN * BK];   // [64][128]  swizzled, 16 KB
    const int bid = blockIdx.x;
    const int wg = (bid & 7) * 96 + (bid >> 3);     // XCD-local A panels
    const int bm = (wg / 24) * BM, bn = (wg % 24) * BN;
    const int t = threadIdx.x, lane = t & 63, wid = t >> 6;
    const int wr = wid >> 1, wc = wid & 1;
    const int lr = lane & 15, lg = lane >> 4;

    f32x4 acc[4][2];
    #pragma unroll
    for (int m = 0; m < 4; ++m)
        #pragma unroll
        for (int n = 0; n < 2; ++n)
            acc[m][n] = (f32x4){0.f, 0.f, 0.f, 0.f};

    for (int kt = 0; kt < DIM; kt += BK) {
        #pragma unroll
        for (int off = 0; off < BM * BK; off += 2048) {
            const int e = off + t * 8, r = e >> 7, c4 = (e & 127) >> 3;
            const int gc = (c4 ^ (r & 7)) << 3;
            gload_lds16(A + (size_t)(bm + r) * DIM + kt + gc, &As[e]);
        }
        #pragma unroll
        for (int off = 0; off < BN * BK; off += 2048) {
            const int e = off + t * 8, r = e >> 7, c4 = (e & 127) >> 3;
            const int gc = (c4 ^ (r & 7)) << 3;
            gload_lds16(B + (size_t)(bn + r) * DIM + kt + gc, &Bs[e]);
        }
        __syncthreads();
        #pragma unroll
        for (int kk = 0; kk < 4; ++kk) {
            short8 af[4], bf[2];
            #pragma unroll
            for (int m = 0; m < 4; ++m) {
                const int row = wr * 64 + m * 16 + lr;
                af[m] = *(const short8*)&As[row * BK + (((kk * 4 + lg) ^ (row & 7)) << 3)];
            }
            #pragma unroll
            for (int n = 0; n < 2; ++n) {
                const int row = wc * 32 + n * 16 + lr;
                bf[n] = *(const short8*)&Bs[row * BK + (((kk * 4 + lg) ^ (row & 7)) << 3)];
            }
            #pragma unroll
            for (int m = 0; m < 4; ++m)
                #pragma unroll
                for (int n = 0; n < 2; ++n)
                    acc[m][n] = __builtin_amdgcn_mfma_f32_16x16x32_bf16(af[m], bf[n], acc[m][n], 0, 0, 0);
        }
        __syncthreads();
    }

    // epilogue: acc -> Tr[128][72] bf16 (reuse As), then packed stores
    unsigned short* Tr = As;
    #pragma unroll
    for (int n = 0; n < 2; ++n) {
        const int cl = wc * 32 + n * 16 + lr;
        const float bv = bias[bn + cl];
        #pragma unroll
        for (int m = 0; m < 4; ++m)
            #pragma unroll
            for (int r = 0; r < 4; ++r)
                Tr[(wr * 64 + m * 16 + lg * 4 + r) * 72 + cl] = f2bf(acc[m][n][r] + bv);
    }
    __syncthreads();

    const int h = bn / 192, ty = (bn >> 6) % 3;
    const int bb = bm >> 11, s0 = bm & 2047;
    if (ty < 2) {   // Q,K: contiguous [s][d] rows
        unsigned short* plane = qkvh + (((size_t)(bb * NH + h) * 3 + ty) * SEQ) * DH;
        const int s = t >> 1, hf = (t & 1) * 32;
        unsigned short* dst = plane + (size_t)(s0 + s) * DH + hf;
        #pragma unroll
        for (int k8 = 0; k8 < 4; ++k8)
            *(short8*)&dst[k8 * 8] = *(const short8*)&Tr[s * 72 + hf + k8 * 8];
    } else {        // V: transposed packed [d][s] stores
        const int d = t >> 2, pp = t & 3;
        unsigned short* vrow = vT + ((size_t)(bb * NH + h) * DH + d) * SEQ + s0 + pp * 32;
        #pragma unroll
        for (int k8 = 0; k8 < 4; ++k8) {
            alignas(16) unsigned short tmp[8];
            #pragma unroll
            for (int k = 0; k < 8; ++k) tmp[k] = Tr[(pp * 32 + k8 * 8 + k) * 72 + d];
            *(short8*)&vrow[k8 * 8] = *(short8*)tmp;
        }
    }
}

// MFMA windowed attention, QT=32, destaged; fixed-trip unrolled loops.
__global__ __launch_bounds__(256)
void attn_mfma(const unsigned short* __restrict__ qkvh,
               const unsigned short* __restrict__ vT,
               const int* __restrict__ pad,
               unsigned short* __restrict__ Yb) {
    const int bid = blockIdx.x;
    const int wg = (bid & 7) * 128 + (bid >> 3);     // XCD-local K/V planes
    const int bh = wg >> 6, qt = wg & 63;
    const int b = bh >> 3, h = bh & 7;
    const int i0 = qt * QT, kb = i0 - HALF;
    const int t = threadIdx.x, lane = t & 63, w = t >> 6;
    const int lr = lane & 15, lg = lane >> 4;

    __shared__ float Sc[QT * SCS2];                  // 37376 B

    const unsigned short* Qg = qkvh + ((size_t)bh * 3 + 0) * SEQ * DH;
    const unsigned short* Kg = qkvh + ((size_t)bh * 3 + 1) * SEQ * DH;
    const unsigned short* vTg = vT + (size_t)bh * DH * SEQ;
    const int* padb = pad + b * SEQ;

    short8 qf[2][2];
    #pragma unroll
    for (int half = 0; half < 2; ++half)
        #pragma unroll
        for (int kk = 0; kk < 2; ++kk)
            qf[half][kk] = *(const short8*)&Qg[(size_t)(i0 + half * 16 + lr) * DH + kk * 32 + lg * 8];

    // ---- scores: fixed 5-trip unrolled loop, guard inside ----
    #pragma unroll
    for (int it = 0; it < 5; ++it) {
        const int tile = w + it * 4;
        if (tile < 18) {
            const int jl = tile * 16 + lr;
            const int j = kb + jl;
            const int jc = j < 0 ? 0 : (j > SEQ - 1 ? SEQ - 1 : j);
            const int kv = (j >= 0 && j < SEQ) ? padb[j] : 0;
            f32x4 a0 = (f32x4){0.f, 0.f, 0.f, 0.f};
            f32x4 a1 = (f32x4){0.f, 0.f, 0.f, 0.f};
            __builtin_amdgcn_s_setprio(1);
            #pragma unroll
            for (int kk = 0; kk < 2; ++kk) {
                const short8 bfr = *(const short8*)&Kg[(size_t)jc * DH + kk * 32 + lg * 8];
                a0 = __builtin_amdgcn_mfma_f32_16x16x32_bf16(qf[0][kk], bfr, a0, 0, 0, 0);
                a1 = __builtin_amdgcn_mfma_f32_16x16x32_bf16(qf[1][kk], bfr, a1, 0, 0, 0);
            }
            __builtin_amdgcn_s_setprio(0);
            #pragma unroll
            for (int r = 0; r < 4; ++r) {
                const int q0 = lg * 4 + r, q1 = 16 + q0;
                const bool ok0 = kv && (jl >= q0) && (jl <= q0 + 2 * HALF);
                const bool ok1 = kv && (jl >= q1) && (jl <= q1 + 2 * HALF);
                Sc[q0 * SCS2 + jl] = ok0 ? a0[r] * 0.125f : -1e30f;
                Sc[q1 * SCS2 + jl] = ok1 ? a1[r] * 0.125f : -1e30f;
            }
        }
    }
    __syncthreads();

    // ---- softmax: fixed 8-trip unrolled; bf16 P written in place ----
    #pragma unroll
    for (int u8 = 0; u8 < 8; ++u8) {
        const int r = w + u8 * 4;
        float* row = &Sc[r * SCS2];
        unsigned short* prow = (unsigned short*)row;
        if (!padb[i0 + r]) {
            #pragma unroll
            for (int u = 0; u < 5; ++u) {
                const int jl = lane + 64 * u;
                if (jl < KW2) prow[jl] = 0;
            }
            continue;
        }
        float v[5];
        float mx = -1e30f;
        #pragma unroll
        for (int u = 0; u < 5; ++u) {
            const int jl = lane + 64 * u;
            v[u] = (jl < KW2) ? row[jl] : -1e30f;
            mx = fmaxf(mx, v[u]);
        }
        #pragma unroll
        for (int off = 32; off; off >>= 1) mx = fmaxf(mx, __shfl_xor(mx, off));
        float s = 0.f;
        #pragma unroll
        for (int u = 0; u < 5; ++u) { v[u] = __expf(v[u] - mx); s += v[u]; }
        #pragma unroll
        for (int off = 32; off; off >>= 1) s += __shfl_xor(s, off);
        const float inv = 1.f / s;
        asm volatile("" ::: "memory");
        #pragma unroll
        for (int u = 0; u < 5; ++u) {
            const int jl = lane + 64 * u;
            if (jl < KW2) prow[jl] = f2bf(v[u] * inv);
        }
    }
    __syncthreads();

    // ---- PV: 9 key-chunks of 32; V fragment shared across both halves ----
    f32x4 o0 = (f32x4){0.f, 0.f, 0.f, 0.f};
    f32x4 o1 = (f32x4){0.f, 0.f, 0.f, 0.f};
    const unsigned short* PbU = (const unsigned short*)Sc;
    const int d0 = w * 16 + lr;
    #pragma unroll
    for (int c = 0; c < 9; ++c) {
        int j0 = kb + c * 32 + lg * 8;
        j0 = j0 < 0 ? 0 : (j0 > SEQ - 8 ? SEQ - 8 : j0);
        const short8 vf  = *(const short8*)&vTg[(size_t)d0 * SEQ + j0];
        const short8 pf0 = *(const short8*)&PbU[lr * (SCS2 * 2) + c * 32 + lg * 8];
        const short8 pf1 = *(const short8*)&PbU[(16 + lr) * (SCS2 * 2) + c * 32 + lg * 8];
        __builtin_amdgcn_s_setprio(1);
        o0 = __builtin_amdgcn_mfma_f32_16x16x32_bf16(pf0, vf, o0, 0, 0, 0);
        o1 = __builtin_amdgcn_mfma_f32_16x16x32_bf16(pf1, vf, o1, 0, 0, 0);
        __builtin_amdgcn_s_setprio(0);
    }

    #pragma unroll
    for (int r = 0; r < 4; ++r) {
        Yb[(size_t)(b * SEQ + i0 + lg * 4 + r) * EMB + h * DH + d0]      = f2bf(o0[r]);
        Yb[(size_t)(b * SEQ + i0 + 16 + lg * 4 + r) * EMB + h * DH + d0] = f2bf(o1[r]);
    }
}

// out = Yb(bf16) @ Wo(bf16)^T + bo. 64x64 tiles, BK=128, 512 blocks.
__global__ __launch_bounds__(256)
void gemm_out(const unsigned short* __restrict__ A, const unsigned short* __restrict__ B,
              const float* __restrict__ bias, float* __restrict__ C) {
    constexpr int BM = 64, BN = 64, BK = 128;
    __shared__ unsigned short As[BM * BK];   // 16 KB
    __shared__ unsigned short Bs[BN * BK];   // 16 KB
    const int bid = blockIdx.x;
    const int wg = (bid & 7) * 64 + (bid >> 3);      // XCD-local A panels
    const int bm = (wg >> 3) * BM, bn = (wg & 7) * BN;
    const int t = threadIdx.x, lane = t & 63, wid = t >> 6;
    const int wr = wid >> 1, wc = wid & 1;
    const int lr = lane & 15, lg = lane >> 4;

    f32x4 acc[2][2];
    #pragma unroll
    for (int m = 0; m < 2; ++m)
        #pragma unroll
        for (int n = 0; n < 2; ++n)
            acc[m][n] = (f32x4){0.f, 0.f, 0.f, 0.f};

    for (int kt = 0; kt < DIM; kt += BK) {
        #pragma unroll
        for (int off = 0; off < BM * BK; off += 2048) {
            const int e = off + t * 8, r = e >> 7, c4 = (e & 127) >> 3;
            const int gc = (c4 ^ (r & 7)) << 3;
            gload_lds16(A + (size_t)(bm + r) * EMB + kt + gc, &As[e]);
        }
        #pragma unroll
        for (int off = 0; off < BN * BK; off += 2048) {
            const int e = off + t * 8, r = e >> 7, c4 = (e & 127) >> 3;
            const int gc = (c4 ^ (r & 7)) << 3;
            gload_lds16(B + (size_t)(bn + r) * DIM + kt + gc, &Bs[e]);
        }
        __syncthreads();
        #pragma unroll
        for (int kk = 0; kk < 4; ++kk) {
            short8 af[2], bf[2];
            #pragma unroll
            for (int m = 0; m < 2; ++m) {
                const int row = wr * 32 + m * 16 + lr;
                af[m] = *(const short8*)&As[row * BK + (((kk * 4 + lg) ^ (row & 7)) << 3)];
            }
            #pragma unroll
            for (int n = 0; n < 2; ++n) {
                const int row = wc * 32 + n * 16 + lr;
                bf[n] = *(const short8*)&Bs[row * BK + (((kk * 4 + lg) ^ (row & 7)) << 3)];
            }
            #pragma unroll
            for (int m = 0; m < 2; ++m)
                #pragma unroll
                for (int n = 0; n < 2; ++n)
                    acc[m][n] = __builtin_amdgcn_mfma_f32_16x16x32_bf16(af[m], bf[n], acc[m][n], 0, 0, 0);
        }
        __syncthreads();
    }

    const int orow = bm + wr * 32 + lg * 4;
    const int oc0 = bn + wc * 32 + lr;
    #pragma unroll
    for (int m = 0; m < 2; ++m)
        #pragma unroll
        for (int n = 0; n < 2; ++n) {
            const int col = oc0 + n * 16;
            const float bv = bias[col];
            #pragma unroll
            for (int r = 0; r < 4; ++r)
                C[(size_t)(orow + m * 16 + r) * EMB + col] = acc[m][n][r] + bv;
        }
}

extern "C" void kernel_launch(void* const* d_in, const int* in_sizes, int n_in,
                              void* d_out, int out_size, void* d_ws, size_t ws_size,
                              hipStream_t stream) {
    const float* x    = (const float*)d_in[0];
    const int*   pad  = (const int*)d_in[1];
    const float* Wqkv = (const float*)d_in[2];
    const float* bqkv = (const float*)d_in[3];
    const float* Wo   = (const float*)d_in[4];
    const float* bo   = (const float*)d_in[5];
    float* out = (float*)d_out;

    char* p = (char*)d_ws;
    unsigned short* qkvh  = (unsigned short*)p;                   // 12.6 MB (Q,K planes)
    unsigned short* vT    = (unsigned short*)(p + 12582912);      // 4 MB
    unsigned short* Yb    = (unsigned short*)(p + 16777216);      // 4 MB
    unsigned short* cvtb  = (unsigned short*)(p + 20971520);      // 6 MB: xb|wqkvb|wob
    unsigned short* xb    = cvtb;
    unsigned short* wqkvb = cvtb + 2097152;
    unsigned short* wob   = cvtb + 2883584;

    dim3 blk(256);
    cvt_all<<<dim3(3072), blk, 0, stream>>>(x, Wqkv, Wo, cvtb);
    gemm_qkv<<<dim3(768), blk, 0, stream>>>(xb, wqkvb, bqkv, qkvh, vT);
    attn_mfma<<<dim3(1024), blk, 0, stream>>>(qkvh, vT, pad, Yb);
    gemm_out<<<dim3(512), blk, 0, stream>>>(Yb, wob, bo, out);
}